// Round 1
// baseline (844.723 us; speedup 1.0000x reference)
//
#include <hip/hip_runtime.h>
#include <hip/hip_bf16.h>

// Problem dims
#define V   50257
#define VPAD 50304          // padded vocab rows for clean 128-tiles (393*128)
#define DD  128
#define HH  256
#define G3  768             // 3*H
#define BB  16
#define TT  128

typedef _Float16 h2   __attribute__((ext_vector_type(2)));
typedef short  bf16x8 __attribute__((ext_vector_type(8)));
typedef float  f32x4  __attribute__((ext_vector_type(4)));

#if __has_builtin(__builtin_amdgcn_fdot2)
#define USE_FDOT2 1
#else
#define USE_FDOT2 0
#endif

__device__ __forceinline__ float sigmoid_(float x) { return 1.0f / (1.0f + __expf(-x)); }
__device__ __forceinline__ float tanh_(float x)    { float e = __expf(2.0f * x); return (e - 1.0f) / (e + 1.0f); }

// ---------------------------------------------------------------------------
// Kernel A: x = embed[ids]; gx = x @ W_ih^T + b_ih   -> gx [2048, 768] fp32
// 256 blocks x 256 threads, 8 token-rows per block.
// ---------------------------------------------------------------------------
__global__ __launch_bounds__(256) void k_embed_gx(
    const int* __restrict__ ids, const float* __restrict__ embed,
    const float* __restrict__ W_ih, const float* __restrict__ b_ih,
    float* __restrict__ gx)
{
    __shared__ float xs[8][DD];
    const int tid  = threadIdx.x;
    const int row0 = blockIdx.x * 8;

#pragma unroll
    for (int i = 0; i < 4; ++i) {
        int e = tid + i * 256;
        int r = e >> 7, k = e & 127;
        int id = ids[row0 + r];
        xs[r][k] = embed[(long)id * DD + k];
    }
    __syncthreads();

#pragma unroll
    for (int o = 0; o < 3; ++o) {
        int j = tid + o * 256;
        float bias = b_ih[j];
        float acc[8];
#pragma unroll
        for (int r = 0; r < 8; ++r) acc[r] = bias;
        const float4* wrow = (const float4*)(W_ih + (long)j * DD);
        for (int q = 0; q < 32; ++q) {
            float4 w = wrow[q];
#pragma unroll
            for (int r = 0; r < 8; ++r) {
                acc[r] += w.x * xs[r][q * 4 + 0] + w.y * xs[r][q * 4 + 1]
                        + w.z * xs[r][q * 4 + 2] + w.w * xs[r][q * 4 + 3];
            }
        }
#pragma unroll
        for (int r = 0; r < 8; ++r) gx[(long)(row0 + r) * G3 + j] = acc[r];
    }
}

// ---------------------------------------------------------------------------
// Kernel W: convert W_out fp32 [50257,256] -> bf16 padded [50304,256]
// pad rows zero-filled. 6288 blocks x 256 threads, 8 elems/thread.
// ---------------------------------------------------------------------------
__global__ __launch_bounds__(256) void k_convert_wout(
    const float* __restrict__ Wout, __hip_bfloat16* __restrict__ Wb)
{
    long base = ((long)blockIdx.x * 256 + threadIdx.x) * 8;
    const long VALID = (long)V * HH;   // 12,865,792 (divisible by 8)
    union { __hip_bfloat16 b[8]; uint4 u; } pk;
    if (base < VALID) {
        float4 f0 = ((const float4*)Wout)[base / 4];
        float4 f1 = ((const float4*)Wout)[base / 4 + 1];
        pk.b[0] = __float2bfloat16(f0.x); pk.b[1] = __float2bfloat16(f0.y);
        pk.b[2] = __float2bfloat16(f0.z); pk.b[3] = __float2bfloat16(f0.w);
        pk.b[4] = __float2bfloat16(f1.x); pk.b[5] = __float2bfloat16(f1.y);
        pk.b[6] = __float2bfloat16(f1.z); pk.b[7] = __float2bfloat16(f1.w);
    } else {
        pk.u = make_uint4(0, 0, 0, 0);
    }
    *(uint4*)(Wb + base) = pk.u;
}

// ---------------------------------------------------------------------------
// Kernel B: GRU recurrence. 16 WGs (one per batch) x 512 threads.
// W_hh register-resident as f16 pairs: thread (g = tid/2, u = tid%2) owns
// rows {g, 256+g, 512+g} x k in [u*128, u*128+128)  -> 192 h2 VGPRs.
// h kept in LDS (fp32 + f16 copy). Pair-reduction via shfl_xor(1).
// Emits h as bf16 [2048,256] for the MFMA head.
// ---------------------------------------------------------------------------
__global__ __launch_bounds__(512, 2) void k_gru(
    const float* __restrict__ gx, const float* __restrict__ W_hh,
    const float* __restrict__ b_hh, __hip_bfloat16* __restrict__ hout)
{
    __shared__ float    hf[HH];
    __shared__ _Float16 hh[HH];
    const int tid = threadIdx.x;
    const int b   = blockIdx.x;
    const int g   = tid >> 1;
    const int u   = tid & 1;

    // one-time: load this thread's W_hh slice into registers as f16 pairs
    h2 w[3][64];
#pragma unroll
    for (int o = 0; o < 3; ++o) {
        const float4* wr = (const float4*)(W_hh + (long)(o * 256 + g) * HH + u * 128);
#pragma unroll
        for (int q = 0; q < 32; ++q) {
            float4 f = wr[q];
            w[o][2 * q]     = h2{(_Float16)f.x, (_Float16)f.y};
            w[o][2 * q + 1] = h2{(_Float16)f.z, (_Float16)f.w};
        }
    }
    float bias[3];
#pragma unroll
    for (int o = 0; o < 3; ++o) bias[o] = b_hh[o * 256 + g];

    if (tid < HH) { hf[tid] = 0.0f; hh[tid] = (_Float16)0.0f; }
    __syncthreads();

    const float* gxrow = gx + (long)b * TT * G3;
    for (int t = 0; t < TT; ++t) {
        // prefetch gate x-side (independent of h, overlaps the matvec)
        float gxr = gxrow[g], gxz = gxrow[256 + g], gxn = gxrow[512 + g];

        float acc0 = 0.f, acc1 = 0.f, acc2 = 0.f;
        const h2* hp = ((const h2*)hh) + u * 64;
#pragma unroll
        for (int p = 0; p < 64; ++p) {
            h2 hv = hp[p];
#if USE_FDOT2
            acc0 = __builtin_amdgcn_fdot2(w[0][p], hv, acc0, false);
            acc1 = __builtin_amdgcn_fdot2(w[1][p], hv, acc1, false);
            acc2 = __builtin_amdgcn_fdot2(w[2][p], hv, acc2, false);
#else
            float hx = (float)hv.x, hy = (float)hv.y;
            acc0 += (float)w[0][p].x * hx + (float)w[0][p].y * hy;
            acc1 += (float)w[1][p].x * hx + (float)w[1][p].y * hy;
            acc2 += (float)w[2][p].x * hx + (float)w[2][p].y * hy;
#endif
        }
        // pair reduce (lanes 2g, 2g+1 within same wave)
        acc0 += __shfl_xor(acc0, 1);
        acc1 += __shfl_xor(acc1, 1);
        acc2 += __shfl_xor(acc2, 1);

        float r = sigmoid_(gxr + acc0 + bias[0]);
        float z = sigmoid_(gxz + acc1 + bias[1]);
        float n = tanh_(gxn + r * (acc2 + bias[2]));
        float hold = hf[g];
        float hnew = (1.0f - z) * n + z * hold;

        __syncthreads();            // all h reads of this step done
        if (u == 0) {
            hf[g] = hnew;
            hh[g] = (_Float16)hnew;
            hout[((long)b * TT + t) * HH + g] = __float2bfloat16(hnew);
        }
        __syncthreads();            // h updated for next step
        gxrow += G3;
    }
}

// ---------------------------------------------------------------------------
// Kernel C: LM head GEMM. C[2048,50257] = A[2048,256] * B[50304,256]^T, bf16
// MFMA 16x16x32, BM=BN=128, BK=64, 256 threads (4 waves, 2x2 of 64x64).
// LDS 16B-chunk XOR swizzle (slot = chunk ^ (row&7)) -> conflict-free frag reads.
// ---------------------------------------------------------------------------
__global__ __launch_bounds__(256) void k_head(
    const __hip_bfloat16* __restrict__ Ah, const __hip_bfloat16* __restrict__ Bw,
    float* __restrict__ out)
{
    __shared__ unsigned short As[128 * 64];
    __shared__ unsigned short Bs[128 * 64];
    const int i    = threadIdx.x;
    const int wave = i >> 6, lane = i & 63;
    const int quad = lane >> 4, mr = lane & 15;
    const int m0   = blockIdx.y * 128;
    const int n0   = blockIdx.x * 128;
    const int wm0  = (wave >> 1) * 64;
    const int wn0  = (wave & 1) * 64;

    f32x4 acc[4][4];
#pragma unroll
    for (int a = 0; a < 4; ++a)
#pragma unroll
        for (int c = 0; c < 4; ++c) acc[a][c] = (f32x4){0.f, 0.f, 0.f, 0.f};

    const uint4* Ag = (const uint4*)Ah;   // row = 32 uint4
    const uint4* Bg = (const uint4*)Bw;
    uint4* Asv = (uint4*)As;
    uint4* Bsv = (uint4*)Bs;

    for (int ks = 0; ks < 4; ++ks) {
        __syncthreads();   // protect LDS from previous iteration's readers
#pragma unroll
        for (int q = 0; q < 4; ++q) {
            int li   = q * 256 + i;
            int row  = li >> 3, slot = li & 7;
            int chunk = slot ^ (row & 7);
            Asv[li] = Ag[(long)(m0 + row) * 32 + ks * 8 + chunk];
            Bsv[li] = Bg[(long)(n0 + row) * 32 + ks * 8 + chunk];
        }
        __syncthreads();
#pragma unroll
        for (int kk = 0; kk < 2; ++kk) {
            bf16x8 af[4], bf[4];
#pragma unroll
            for (int wmi = 0; wmi < 4; ++wmi) {
                int row  = wm0 + wmi * 16 + mr;
                int slot = (kk * 4 + quad) ^ (row & 7);
                af[wmi] = *(const bf16x8*)&As[(row * 8 + slot) * 8];
            }
#pragma unroll
            for (int wni = 0; wni < 4; ++wni) {
                int row  = wn0 + wni * 16 + mr;
                int slot = (kk * 4 + quad) ^ (row & 7);
                bf[wni] = *(const bf16x8*)&Bs[(row * 8 + slot) * 8];
            }
#pragma unroll
            for (int wmi = 0; wmi < 4; ++wmi)
#pragma unroll
                for (int wni = 0; wni < 4; ++wni)
                    acc[wmi][wni] = __builtin_amdgcn_mfma_f32_16x16x32_bf16(
                        af[wmi], bf[wni], acc[wmi][wni], 0, 0, 0);
        }
    }

    // epilogue: C/D layout col = lane&15, row = quad*4 + reg
#pragma unroll
    for (int wmi = 0; wmi < 4; ++wmi) {
#pragma unroll
        for (int rr = 0; rr < 4; ++rr) {
            long m = m0 + wm0 + wmi * 16 + quad * 4 + rr;
            float* orow = out + m * (long)V;
#pragma unroll
            for (int wni = 0; wni < 4; ++wni) {
                int n = n0 + wn0 + wni * 16 + mr;
                if (n < V) orow[n] = acc[wmi][wni][rr];
            }
        }
    }
}

// ---------------------------------------------------------------------------
extern "C" void kernel_launch(void* const* d_in, const int* in_sizes, int n_in,
                              void* d_out, int out_size, void* d_ws, size_t ws_size,
                              hipStream_t stream) {
    const int*   ids   = (const int*)d_in[0];
    const float* embed = (const float*)d_in[1];
    const float* W_ih  = (const float*)d_in[2];
    const float* b_ih  = (const float*)d_in[3];
    const float* W_hh  = (const float*)d_in[4];
    const float* b_hh  = (const float*)d_in[5];
    const float* W_out = (const float*)d_in[6];
    float* out = (float*)d_out;

    // workspace layout (ws re-poisoned each launch; everything rewritten here)
    char* ws = (char*)d_ws;
    float*          gx  = (float*)ws;                           // 2048*768*4   = 6,291,456 B
    __hip_bfloat16* hbf = (__hip_bfloat16*)(ws + 6291456);      // 2048*256*2   = 1,048,576 B
    __hip_bfloat16* wbf = (__hip_bfloat16*)(ws + 7340032);      // 50304*256*2  = 25,755,648 B

    k_embed_gx<<<256, 256, 0, stream>>>(ids, embed, W_ih, b_ih, gx);
    k_convert_wout<<<6288, 256, 0, stream>>>(W_out, wbf);
    k_gru<<<16, 512, 0, stream>>>(gx, W_hh, b_hh, hbf);
    k_head<<<dim3(393, 16), 256, 0, stream>>>(hbf, wbf, out);
}

// Round 2
// 773.723 us; speedup vs baseline: 1.0918x; 1.0918x over previous
//
#include <hip/hip_runtime.h>
#include <hip/hip_bf16.h>

// Problem dims
#define V    50257
#define VPAD 50304          // padded vocab rows for clean 128-tiles (393*128)
#define DD   128
#define HH   256
#define G3   768            // 3*H
#define BB   16
#define TT   128

typedef _Float16 h2   __attribute__((ext_vector_type(2)));
typedef _Float16 h8   __attribute__((ext_vector_type(8)));
typedef short  bf16x8 __attribute__((ext_vector_type(8)));
typedef float  f32x4  __attribute__((ext_vector_type(4)));

typedef __attribute__((address_space(3))) uint4* lds_u4_t;
typedef const __attribute__((address_space(1))) uint4* gbl_u4_t;

__device__ __forceinline__ void async_copy16(const uint4* g, uint4* lds_base) {
    // LDS dest = wave-uniform base + lane*16 (per-lane global scatter is OK)
    __builtin_amdgcn_global_load_lds((gbl_u4_t)g, (lds_u4_t)lds_base, 16, 0, 0);
}

#if __has_builtin(__builtin_amdgcn_fdot2)
#define USE_FDOT2 1
#else
#define USE_FDOT2 0
#endif

__device__ __forceinline__ float sigmoid_(float x) { return 1.0f / (1.0f + __expf(-x)); }
__device__ __forceinline__ float tanh_(float x)    { float e = __expf(2.0f * x); return (e - 1.0f) / (e + 1.0f); }

// ---------------------------------------------------------------------------
// Kernel A: x = embed[ids]; gx = x @ W_ih^T + b_ih   -> gx [2048, 768] fp32
// ---------------------------------------------------------------------------
__global__ __launch_bounds__(256) void k_embed_gx(
    const int* __restrict__ ids, const float* __restrict__ embed,
    const float* __restrict__ W_ih, const float* __restrict__ b_ih,
    float* __restrict__ gx)
{
    __shared__ float xs[8][DD];
    const int tid  = threadIdx.x;
    const int row0 = blockIdx.x * 8;

#pragma unroll
    for (int i = 0; i < 4; ++i) {
        int e = tid + i * 256;
        int r = e >> 7, k = e & 127;
        int id = ids[row0 + r];
        xs[r][k] = embed[(long)id * DD + k];
    }
    __syncthreads();

#pragma unroll
    for (int o = 0; o < 3; ++o) {
        int j = tid + o * 256;
        float bias = b_ih[j];
        float acc[8];
#pragma unroll
        for (int r = 0; r < 8; ++r) acc[r] = bias;
        const float4* wrow = (const float4*)(W_ih + (long)j * DD);
        for (int q = 0; q < 32; ++q) {
            float4 w = wrow[q];
#pragma unroll
            for (int r = 0; r < 8; ++r) {
                acc[r] += w.x * xs[r][q * 4 + 0] + w.y * xs[r][q * 4 + 1]
                        + w.z * xs[r][q * 4 + 2] + w.w * xs[r][q * 4 + 3];
            }
        }
#pragma unroll
        for (int r = 0; r < 8; ++r) gx[(long)(row0 + r) * G3 + j] = acc[r];
    }
}

// ---------------------------------------------------------------------------
// Kernel W: convert W_out fp32 [50257,256] -> bf16 padded [50304,256]
// ---------------------------------------------------------------------------
__global__ __launch_bounds__(256) void k_convert_wout(
    const float* __restrict__ Wout, __hip_bfloat16* __restrict__ Wb)
{
    long base = ((long)blockIdx.x * 256 + threadIdx.x) * 8;
    const long VALID = (long)V * HH;   // 12,865,792 (divisible by 8)
    union { __hip_bfloat16 b[8]; uint4 u; } pk;
    if (base < VALID) {
        float4 f0 = ((const float4*)Wout)[base / 4];
        float4 f1 = ((const float4*)Wout)[base / 4 + 1];
        pk.b[0] = __float2bfloat16(f0.x); pk.b[1] = __float2bfloat16(f0.y);
        pk.b[2] = __float2bfloat16(f0.z); pk.b[3] = __float2bfloat16(f0.w);
        pk.b[4] = __float2bfloat16(f1.x); pk.b[5] = __float2bfloat16(f1.y);
        pk.b[6] = __float2bfloat16(f1.z); pk.b[7] = __float2bfloat16(f1.w);
    } else {
        pk.u = make_uint4(0, 0, 0, 0);
    }
    *(uint4*)(Wb + base) = pk.u;
}

// ---------------------------------------------------------------------------
// Kernel B: GRU recurrence. 16 WGs (one per batch) x 512 threads.
// W_hh register-resident as f16 pairs: thread (g = tid/2, u = tid%2) owns
// rows {g, 256+g, 512+g} x k in [u*128, u*128+128)  -> 192 h2 VGPRs.
// h double-buffered in LDS (f16) -> ONE barrier per step. h_old carried in a
// register (every thread recomputes its own hnew). 2 acc chains per gate.
// ---------------------------------------------------------------------------
__global__ __launch_bounds__(512, 2) void k_gru(
    const float* __restrict__ gx, const float* __restrict__ W_hh,
    const float* __restrict__ b_hh, __hip_bfloat16* __restrict__ hout)
{
    __shared__ _Float16 hh[2][HH];
    const int tid = threadIdx.x;
    const int b   = blockIdx.x;
    const int g   = tid >> 1;
    const int u   = tid & 1;

    // one-time: load this thread's W_hh slice into registers as f16 pairs
    h2 w[3][64];
#pragma unroll
    for (int o = 0; o < 3; ++o) {
        const float4* wr = (const float4*)(W_hh + (long)(o * 256 + g) * HH + u * 128);
#pragma unroll
        for (int q = 0; q < 32; ++q) {
            float4 f = wr[q];
            w[o][2 * q]     = h2{(_Float16)f.x, (_Float16)f.y};
            w[o][2 * q + 1] = h2{(_Float16)f.z, (_Float16)f.w};
        }
    }
    float bias[3];
#pragma unroll
    for (int o = 0; o < 3; ++o) bias[o] = b_hh[o * 256 + g];

    if (tid < HH) hh[0][tid] = (_Float16)0.0f;
    __syncthreads();

    const float* gxrow = gx + (long)b * TT * G3;
    // software-pipelined gx loads
    float cxr = gxrow[g], cxz = gxrow[256 + g], cxn = gxrow[512 + g];
    float hold = 0.0f;

    for (int t = 0; t < TT; ++t) {
        // issue next step's gx loads early (reads at t=127 land in ws scratch
        // past gx's region -> valid memory, value discarded)
        const float* nrow = gxrow + G3;
        float nxr = nrow[g], nxz = nrow[256 + g], nxn = nrow[512 + g];

        float a0a = 0.f, a0b = 0.f, a1a = 0.f, a1b = 0.f, a2a = 0.f, a2b = 0.f;
        const h8* hp8 = ((const h8*)hh[t & 1]) + u * 16;   // 16 x 16B chunks
#pragma unroll
        for (int c = 0; c < 16; ++c) {
            h8 hv = hp8[c];
            const h2* hvp = (const h2*)&hv;
#pragma unroll
            for (int j = 0; j < 4; ++j) {
                h2 hq = hvp[j];
                int p = c * 4 + j;
#if USE_FDOT2
                if (j & 1) {
                    a0b = __builtin_amdgcn_fdot2(w[0][p], hq, a0b, false);
                    a1b = __builtin_amdgcn_fdot2(w[1][p], hq, a1b, false);
                    a2b = __builtin_amdgcn_fdot2(w[2][p], hq, a2b, false);
                } else {
                    a0a = __builtin_amdgcn_fdot2(w[0][p], hq, a0a, false);
                    a1a = __builtin_amdgcn_fdot2(w[1][p], hq, a1a, false);
                    a2a = __builtin_amdgcn_fdot2(w[2][p], hq, a2a, false);
                }
#else
                float hx = (float)hq.x, hy = (float)hq.y;
                if (j & 1) {
                    a0b += (float)w[0][p].x * hx + (float)w[0][p].y * hy;
                    a1b += (float)w[1][p].x * hx + (float)w[1][p].y * hy;
                    a2b += (float)w[2][p].x * hx + (float)w[2][p].y * hy;
                } else {
                    a0a += (float)w[0][p].x * hx + (float)w[0][p].y * hy;
                    a1a += (float)w[1][p].x * hx + (float)w[1][p].y * hy;
                    a2a += (float)w[2][p].x * hx + (float)w[2][p].y * hy;
                }
#endif
            }
        }
        float acc0 = a0a + a0b, acc1 = a1a + a1b, acc2 = a2a + a2b;
        // pair reduce (lanes 2g, 2g+1 in same wave)
        acc0 += __shfl_xor(acc0, 1);
        acc1 += __shfl_xor(acc1, 1);
        acc2 += __shfl_xor(acc2, 1);

        float r = sigmoid_(cxr + acc0 + bias[0]);
        float z = sigmoid_(cxz + acc1 + bias[1]);
        float n = tanh_(cxn + r * (acc2 + bias[2]));
        float hnew = (1.0f - z) * n + z * hold;

        // u==0 writes next h buffer, u==1 writes the bf16 output (parallel)
        if (u == 0) hh[(t + 1) & 1][g] = (_Float16)hnew;
        else        hout[((long)b * TT + t) * HH + g] = __float2bfloat16(hnew);
        __syncthreads();   // single barrier: next buffer ready, this one free

        hold = hnew;
        cxr = nxr; cxz = nxz; cxn = nxn;
        gxrow = nrow;
    }
}

// ---------------------------------------------------------------------------
// Kernel C: LM head GEMM. C[2048,50257] = A[2048,256] * B[50304,256]^T, bf16
// MFMA 16x16x32, BM=BN=128, BK=64, 256 threads (4 waves, 2x2 of 64x64).
// global_load_lds width-16 staging; XOR swizzle moved to the GLOBAL address
// side (LDS dest must be lane-linear), identical LDS layout to v1:
//   LDS slot li holds global 16B-chunk (li&7)^(row&7) of row li>>3.
// ---------------------------------------------------------------------------
__global__ __launch_bounds__(256) void k_head(
    const __hip_bfloat16* __restrict__ Ah, const __hip_bfloat16* __restrict__ Bw,
    float* __restrict__ out)
{
    __shared__ unsigned short As[128 * 64];
    __shared__ unsigned short Bs[128 * 64];
    const int i    = threadIdx.x;
    const int wave = i >> 6, lane = i & 63;
    const int quad = lane >> 4, mr = lane & 15;
    const int m0   = blockIdx.y * 128;
    const int n0   = blockIdx.x * 128;
    const int wm0  = (wave >> 1) * 64;
    const int wn0  = (wave & 1) * 64;

    f32x4 acc[4][4];
#pragma unroll
    for (int a = 0; a < 4; ++a)
#pragma unroll
        for (int c = 0; c < 4; ++c) acc[a][c] = (f32x4){0.f, 0.f, 0.f, 0.f};

    const uint4* Ag = (const uint4*)Ah;   // row = 32 uint4 (256 bf16)
    const uint4* Bg = (const uint4*)Bw;
    uint4* Asv = (uint4*)As;
    uint4* Bsv = (uint4*)Bs;

    // Precompute per-lane global base addresses + wave-uniform LDS bases.
    // Segment seg = c*4 + wave covers LDS slots [seg*64, seg*64+64).
    const uint4* agp[4]; const uint4* bgp[4];
    uint4* alds[4]; uint4* blds[4];
#pragma unroll
    for (int c = 0; c < 4; ++c) {
        int seg   = c * 4 + wave;
        int row   = seg * 8 + (lane >> 3);
        int chunk = (lane & 7) ^ (row & 7);
        agp[c] = Ag + (long)(m0 + row) * 32 + chunk;
        bgp[c] = Bg + (long)(n0 + row) * 32 + chunk;
        alds[c] = Asv + seg * 64;   // + lane*16B implicit in global_load_lds
        blds[c] = Bsv + seg * 64;
    }

    for (int ks = 0; ks < 4; ++ks) {
        __syncthreads();   // previous iteration's LDS readers done
#pragma unroll
        for (int c = 0; c < 4; ++c) async_copy16(agp[c] + ks * 8, alds[c]);
#pragma unroll
        for (int c = 0; c < 4; ++c) async_copy16(bgp[c] + ks * 8, blds[c]);
        __syncthreads();   // compiler emits s_waitcnt vmcnt(0) before barrier

#pragma unroll
        for (int kk = 0; kk < 2; ++kk) {
            bf16x8 af[4], bf[4];
#pragma unroll
            for (int wmi = 0; wmi < 4; ++wmi) {
                int row  = wm0 + wmi * 16 + mr;
                int slot = (kk * 4 + quad) ^ (row & 7);
                af[wmi] = *(const bf16x8*)&As[(row * 8 + slot) * 8];
            }
#pragma unroll
            for (int wni = 0; wni < 4; ++wni) {
                int row  = wn0 + wni * 16 + mr;
                int slot = (kk * 4 + quad) ^ (row & 7);
                bf[wni] = *(const bf16x8*)&Bs[(row * 8 + slot) * 8];
            }
#pragma unroll
            for (int wmi = 0; wmi < 4; ++wmi)
#pragma unroll
                for (int wni = 0; wni < 4; ++wni)
                    acc[wmi][wni] = __builtin_amdgcn_mfma_f32_16x16x32_bf16(
                        af[wmi], bf[wni], acc[wmi][wni], 0, 0, 0);
        }
    }

    // epilogue: C/D layout col = lane&15, row = quad*4 + reg
#pragma unroll
    for (int wmi = 0; wmi < 4; ++wmi) {
#pragma unroll
        for (int rr = 0; rr < 4; ++rr) {
            long m = m0 + wm0 + wmi * 16 + quad * 4 + rr;
            float* orow = out + m * (long)V;
#pragma unroll
            for (int wni = 0; wni < 4; ++wni) {
                int n = n0 + wn0 + wni * 16 + mr;
                if (n < V) orow[n] = acc[wmi][wni][rr];
            }
        }
    }
}

// ---------------------------------------------------------------------------
extern "C" void kernel_launch(void* const* d_in, const int* in_sizes, int n_in,
                              void* d_out, int out_size, void* d_ws, size_t ws_size,
                              hipStream_t stream) {
    const int*   ids   = (const int*)d_in[0];
    const float* embed = (const float*)d_in[1];
    const float* W_ih  = (const float*)d_in[2];
    const float* b_ih  = (const float*)d_in[3];
    const float* W_hh  = (const float*)d_in[4];
    const float* b_hh  = (const float*)d_in[5];
    const float* W_out = (const float*)d_in[6];
    float* out = (float*)d_out;

    // workspace layout (ws re-poisoned each launch; everything rewritten here)
    char* ws = (char*)d_ws;
    float*          gx  = (float*)ws;                           // 2048*768*4   = 6,291,456 B
    __hip_bfloat16* hbf = (__hip_bfloat16*)(ws + 6291456);      // 2048*256*2   = 1,048,576 B
    __hip_bfloat16* wbf = (__hip_bfloat16*)(ws + 7340032);      // 50304*256*2  = 25,755,648 B

    k_embed_gx<<<256, 256, 0, stream>>>(ids, embed, W_ih, b_ih, gx);
    k_convert_wout<<<6288, 256, 0, stream>>>(W_out, wbf);
    k_gru<<<16, 512, 0, stream>>>(gx, W_hh, b_hh, hbf);
    k_head<<<dim3(393, 16), 256, 0, stream>>>(hbf, wbf, out);
}